// Round 3
// baseline (6879.896 us; speedup 1.0000x reference)
//
#include <hip/hip_runtime.h>
#include <hip/hip_bf16.h>

#define P_TOT 65536
#define DIM   384
#define KCL   64
#define ITERS 10
#define GACC  16   // point-slices for accumulation

// All tensors fp32 (per reference). d_ws layout (floats):
// centers[24576] | sums[24576] | cnorm[64] | cnt[64] | CW[24576]  ~= 295 KB.
// labels (int[65536]) lives at the head of d_out (dead before final_kernel,
// which overwrites all of d_out and never reads labels).

// centers0 = points[:64]; cnorm[c] = ||center||^2 ; zero sums/cnt
__global__ __launch_bounds__(384) void init_kernel(const float* __restrict__ x,
                                                   float* __restrict__ centers,
                                                   float* __restrict__ sums,
                                                   float* __restrict__ cnorm,
                                                   float* __restrict__ cnt) {
    __shared__ float red[384];
    const int c = blockIdx.x, t = threadIdx.x;
    float v = x[(size_t)c * DIM + t];
    centers[(size_t)c * DIM + t] = v;
    sums[(size_t)c * DIM + t] = 0.f;
    if (t == 0) cnt[c] = 0.f;
    red[t] = v * v;
    __syncthreads();
    if (t < 128) red[t] = red[t] + red[t + 128] + red[t + 256];
    __syncthreads();
    for (int s = 64; s > 0; s >>= 1) {
        if (t < s) red[t] += red[t + s];
        __syncthreads();
    }
    if (t == 0) cnorm[c] = red[0];
}

// labels[p] = argmin_c (cnorm[c] - 2*dot(p,c)); 64 points x 64 clusters per block
__global__ __launch_bounds__(256) void assign_kernel(const float* __restrict__ x,
                                                     const float* __restrict__ centers,
                                                     const float* __restrict__ cnorm,
                                                     int* __restrict__ labels) {
    __shared__ float At[32][68];   // [kk][point]
    __shared__ float Bt[32][68];   // [kk][cluster]
    __shared__ float rv[64][16];
    __shared__ int   rc[64][16];
    const int t  = threadIdx.x;
    const int tx = t & 15;         // cluster group (4 clusters)
    const int ty = t >> 4;         // point group (4 points)
    const int p0 = blockIdx.x * 64;
    const int lp = t >> 2;         // 0..63: row to stage
    const int lk = (t & 3) * 8;    // dim offset within k-tile

    float acc[4][4];
#pragma unroll
    for (int i = 0; i < 4; ++i)
#pragma unroll
        for (int j = 0; j < 4; ++j) acc[i][j] = 0.f;

    for (int kt = 0; kt < 12; ++kt) {
        const int k0 = kt * 32;
        float4 a0 = *(const float4*)(x + (size_t)(p0 + lp) * DIM + k0 + lk);
        float4 a1 = *(const float4*)(x + (size_t)(p0 + lp) * DIM + k0 + lk + 4);
        At[lk + 0][lp] = a0.x; At[lk + 1][lp] = a0.y;
        At[lk + 2][lp] = a0.z; At[lk + 3][lp] = a0.w;
        At[lk + 4][lp] = a1.x; At[lk + 5][lp] = a1.y;
        At[lk + 6][lp] = a1.z; At[lk + 7][lp] = a1.w;
        float4 b0 = *(const float4*)(centers + (size_t)lp * DIM + k0 + lk);
        float4 b1 = *(const float4*)(centers + (size_t)lp * DIM + k0 + lk + 4);
        Bt[lk + 0][lp] = b0.x; Bt[lk + 1][lp] = b0.y;
        Bt[lk + 2][lp] = b0.z; Bt[lk + 3][lp] = b0.w;
        Bt[lk + 4][lp] = b1.x; Bt[lk + 5][lp] = b1.y;
        Bt[lk + 6][lp] = b1.z; Bt[lk + 7][lp] = b1.w;
        __syncthreads();
#pragma unroll
        for (int kk = 0; kk < 32; ++kk) {
            float4 a4 = *(const float4*)&At[kk][ty * 4];
            float4 b4 = *(const float4*)&Bt[kk][tx * 4];
            float av[4] = {a4.x, a4.y, a4.z, a4.w};
            float bv[4] = {b4.x, b4.y, b4.z, b4.w};
#pragma unroll
            for (int i = 0; i < 4; ++i)
#pragma unroll
                for (int j = 0; j < 4; ++j) acc[i][j] += av[i] * bv[j];
        }
        __syncthreads();
    }

    float cn[4];
#pragma unroll
    for (int j = 0; j < 4; ++j) cn[j] = cnorm[tx * 4 + j];
#pragma unroll
    for (int i = 0; i < 4; ++i) {
        float bv = 3.4e38f; int bc = 0;
#pragma unroll
        for (int j = 0; j < 4; ++j) {
            float d = cn[j] - 2.0f * acc[i][j];
            if (d < bv) { bv = d; bc = tx * 4 + j; }  // strict <: lowest index wins ties
        }
        rv[ty * 4 + i][tx] = bv;
        rc[ty * 4 + i][tx] = bc;
    }
    __syncthreads();
    if (t < 64) {
        float bv = rv[t][0]; int bc = rc[t][0];
#pragma unroll
        for (int xx = 1; xx < 16; ++xx) {
            float v = rv[t][xx];
            if (v < bv) { bv = v; bc = rc[t][xx]; }  // ascending tx: lowest cluster wins ties
        }
        labels[p0 + t] = bc;
    }
}

// per-(cluster, point-slice) LDS partial sums -> global atomicAdd into sums/cnt
__global__ __launch_bounds__(256) void accum_kernel(const float* __restrict__ x,
                                                    const int* __restrict__ labels,
                                                    float* __restrict__ sums,
                                                    float* __restrict__ cnt) {
    __shared__ float lsum[DIM];
    __shared__ int   lcnt;
    const int t = threadIdx.x;
    const int c = blockIdx.x, g = blockIdx.y;
    if (t < 192) { lsum[t] = 0.f; lsum[t + 192] = 0.f; }
    if (t == 0) lcnt = 0;
    __syncthreads();
    const int pbase = g * (P_TOT / GACC);
    for (int ch = 0; ch < (P_TOT / GACC) / 256; ++ch) {
        const int p = pbase + ch * 256 + t;
        if (labels[p] == c) {
            atomicAdd(&lcnt, 1);
            const float* xp = x + (size_t)p * DIM;
            const int s0 = t % 96;  // stagger to spread LDS atomic contention
            for (int i = 0; i < 96; ++i) {
                int dg = s0 + i; if (dg >= 96) dg -= 96;
                float4 v = *(const float4*)(xp + dg * 4);
                atomicAdd(&lsum[dg * 4 + 0], v.x);
                atomicAdd(&lsum[dg * 4 + 1], v.y);
                atomicAdd(&lsum[dg * 4 + 2], v.z);
                atomicAdd(&lsum[dg * 4 + 3], v.w);
            }
        }
    }
    __syncthreads();
    if (t < 192) {
        atomicAdd(&sums[(size_t)c * DIM + t],       lsum[t]);
        atomicAdd(&sums[(size_t)c * DIM + t + 192], lsum[t + 192]);
    }
    if (t == 0 && lcnt > 0) atomicAdd(&cnt[c], (float)lcnt);
}

// centers[c] = cnt>0 ? sums/cnt : old ; cnorm ; re-zero sums/cnt for next iter
__global__ __launch_bounds__(384) void update_kernel(float* __restrict__ sums,
                                                     float* __restrict__ cnt,
                                                     float* __restrict__ centers,
                                                     float* __restrict__ cnorm) {
    __shared__ float red[384];
    const int c = blockIdx.x, t = threadIdx.x;
    float s = sums[(size_t)c * DIM + t];
    float n = cnt[c];
    float oldv = centers[(size_t)c * DIM + t];
    float nc = (n > 0.f) ? (s / n) : oldv;
    centers[(size_t)c * DIM + t] = nc;
    sums[(size_t)c * DIM + t] = 0.f;
    if (t == 0) cnt[c] = 0.f;
    red[t] = nc * nc;
    __syncthreads();
    if (t < 128) red[t] = red[t] + red[t + 128] + red[t + 256];
    __syncthreads();
    for (int st = 64; st > 0; st >>= 1) {
        if (t < st) red[t] += red[t + st];
        __syncthreads();
    }
    if (t == 0) cnorm[c] = red[0];
}

// CW[c][j] = b[j] + sum_d centers[c][d] * W[j][d]
__global__ __launch_bounds__(384) void cw_kernel(const float* __restrict__ centers,
                                                 const float* __restrict__ W,
                                                 const float* __restrict__ b,
                                                 float* __restrict__ CW) {
    __shared__ float cs[DIM];
    const int c = blockIdx.x, j = threadIdx.x;
    cs[j] = centers[(size_t)c * DIM + j];
    __syncthreads();
    float acc = b[j];
    const float* wr = W + (size_t)j * DIM;
    for (int d4 = 0; d4 < 96; ++d4) {
        float4 v = *(const float4*)(wr + d4 * 4);
        acc += cs[d4 * 4 + 0] * v.x + cs[d4 * 4 + 1] * v.y
             + cs[d4 * 4 + 2] * v.z + cs[d4 * 4 + 3] * v.w;
    }
    CW[(size_t)c * DIM + j] = acc;
}

// fused final assignment + output write: out[p][:] = CW[argmin_c d(p,c)][:]
__global__ __launch_bounds__(256) void final_kernel(const float* __restrict__ x,
                                                    const float* __restrict__ centers,
                                                    const float* __restrict__ cnorm,
                                                    const float* __restrict__ CW,
                                                    float* __restrict__ out) {
    __shared__ float At[32][68];
    __shared__ float Bt[32][68];
    __shared__ float rv[64][16];
    __shared__ int   rc[64][16];
    __shared__ int   lab[64];
    const int t  = threadIdx.x;
    const int tx = t & 15;
    const int ty = t >> 4;
    const int p0 = blockIdx.x * 64;
    const int lp = t >> 2;
    const int lk = (t & 3) * 8;

    float acc[4][4];
#pragma unroll
    for (int i = 0; i < 4; ++i)
#pragma unroll
        for (int j = 0; j < 4; ++j) acc[i][j] = 0.f;

    for (int kt = 0; kt < 12; ++kt) {
        const int k0 = kt * 32;
        float4 a0 = *(const float4*)(x + (size_t)(p0 + lp) * DIM + k0 + lk);
        float4 a1 = *(const float4*)(x + (size_t)(p0 + lp) * DIM + k0 + lk + 4);
        At[lk + 0][lp] = a0.x; At[lk + 1][lp] = a0.y;
        At[lk + 2][lp] = a0.z; At[lk + 3][lp] = a0.w;
        At[lk + 4][lp] = a1.x; At[lk + 5][lp] = a1.y;
        At[lk + 6][lp] = a1.z; At[lk + 7][lp] = a1.w;
        float4 b0 = *(const float4*)(centers + (size_t)lp * DIM + k0 + lk);
        float4 b1 = *(const float4*)(centers + (size_t)lp * DIM + k0 + lk + 4);
        Bt[lk + 0][lp] = b0.x; Bt[lk + 1][lp] = b0.y;
        Bt[lk + 2][lp] = b0.z; Bt[lk + 3][lp] = b0.w;
        Bt[lk + 4][lp] = b1.x; Bt[lk + 5][lp] = b1.y;
        Bt[lk + 6][lp] = b1.z; Bt[lk + 7][lp] = b1.w;
        __syncthreads();
#pragma unroll
        for (int kk = 0; kk < 32; ++kk) {
            float4 a4 = *(const float4*)&At[kk][ty * 4];
            float4 b4 = *(const float4*)&Bt[kk][tx * 4];
            float av[4] = {a4.x, a4.y, a4.z, a4.w};
            float bv[4] = {b4.x, b4.y, b4.z, b4.w};
#pragma unroll
            for (int i = 0; i < 4; ++i)
#pragma unroll
                for (int j = 0; j < 4; ++j) acc[i][j] += av[i] * bv[j];
        }
        __syncthreads();
    }

    float cn[4];
#pragma unroll
    for (int j = 0; j < 4; ++j) cn[j] = cnorm[tx * 4 + j];
#pragma unroll
    for (int i = 0; i < 4; ++i) {
        float bv = 3.4e38f; int bc = 0;
#pragma unroll
        for (int j = 0; j < 4; ++j) {
            float d = cn[j] - 2.0f * acc[i][j];
            if (d < bv) { bv = d; bc = tx * 4 + j; }
        }
        rv[ty * 4 + i][tx] = bv;
        rc[ty * 4 + i][tx] = bc;
    }
    __syncthreads();
    if (t < 64) {
        float bv = rv[t][0]; int bc = rc[t][0];
#pragma unroll
        for (int xx = 1; xx < 16; ++xx) {
            float v = rv[t][xx];
            if (v < bv) { bv = v; bc = rc[t][xx]; }
        }
        lab[t] = bc;
    }
    __syncthreads();
    // write 64 points x 384 floats = 6144 float4 chunks; 24 per thread
#pragma unroll
    for (int r = 0; r < 24; ++r) {
        const int q = r * 256 + t;
        const int pp = q / 96;
        const int jg = q - pp * 96;
        float4 v = *(const float4*)(CW + (size_t)lab[pp] * DIM + jg * 4);
        *(float4*)(out + (size_t)(p0 + pp) * DIM + jg * 4) = v;
    }
}

extern "C" void kernel_launch(void* const* d_in, const int* in_sizes, int n_in,
                              void* d_out, int out_size, void* d_ws, size_t ws_size,
                              hipStream_t stream) {
    const float* x = (const float*)d_in[0];  // fp32 (16,4096,384)
    const float* W = (const float*)d_in[1];  // fp32 (384,384)
    const float* b = (const float*)d_in[2];  // fp32 (384,)
    float* out = (float*)d_out;              // fp32 (16,4096,384)

    float* centers = (float*)d_ws;                 // 64*384
    float* sums    = centers + KCL * DIM;          // 64*384
    float* cnorm   = sums + KCL * DIM;             // 64
    float* cnt     = cnorm + KCL;                  // 64
    float* CW      = cnt + KCL;                    // 64*384
    int* labels = (int*)d_out;                     // head of d_out (dead before final)

    init_kernel<<<KCL, 384, 0, stream>>>(x, centers, sums, cnorm, cnt);
    for (int it = 0; it < ITERS; ++it) {
        assign_kernel<<<P_TOT / 64, 256, 0, stream>>>(x, centers, cnorm, labels);
        accum_kernel<<<dim3(KCL, GACC), 256, 0, stream>>>(x, labels, sums, cnt);
        update_kernel<<<KCL, 384, 0, stream>>>(sums, cnt, centers, cnorm);
    }
    cw_kernel<<<KCL, 384, 0, stream>>>(centers, W, b, CW);
    final_kernel<<<P_TOT / 64, 256, 0, stream>>>(x, centers, cnorm, CW, out);
}

// Round 4
// 1415.015 us; speedup vs baseline: 4.8621x; 4.8621x over previous
//
#include <hip/hip_runtime.h>
#include <hip/hip_bf16.h>

#define P_TOT 65536
#define DIM   384
#define KCL   64
#define ITERS 10
#define APTS  256   // points per accum block

// All tensors fp32 (per reference). d_ws layout (floats):
// centers[24576] | sums[24576] | cnorm[64] | cnt[64] | CW[24576]  ~= 295 KB.
// labels (int[65536]) lives at the head of d_out (dead before final_kernel,
// which overwrites all of d_out and never reads labels).

// centers0 = points[:64]; cnorm[c] = ||center||^2 ; zero sums/cnt
__global__ __launch_bounds__(384) void init_kernel(const float* __restrict__ x,
                                                   float* __restrict__ centers,
                                                   float* __restrict__ sums,
                                                   float* __restrict__ cnorm,
                                                   float* __restrict__ cnt) {
    __shared__ float red[384];
    const int c = blockIdx.x, t = threadIdx.x;
    float v = x[(size_t)c * DIM + t];
    centers[(size_t)c * DIM + t] = v;
    sums[(size_t)c * DIM + t] = 0.f;
    if (t == 0) cnt[c] = 0.f;
    red[t] = v * v;
    __syncthreads();
    if (t < 128) red[t] = red[t] + red[t + 128] + red[t + 256];
    __syncthreads();
    for (int s = 64; s > 0; s >>= 1) {
        if (t < s) red[t] += red[t + s];
        __syncthreads();
    }
    if (t == 0) cnorm[c] = red[0];
}

// labels[p] = argmin_c (cnorm[c] - 2*dot(p,c)); 64 points x 64 clusters per block
__global__ __launch_bounds__(256) void assign_kernel(const float* __restrict__ x,
                                                     const float* __restrict__ centers,
                                                     const float* __restrict__ cnorm,
                                                     int* __restrict__ labels) {
    __shared__ float At[32][68];   // [kk][point]
    __shared__ float Bt[32][68];   // [kk][cluster]
    __shared__ float rv[64][16];
    __shared__ int   rc[64][16];
    const int t  = threadIdx.x;
    const int tx = t & 15;         // cluster group (4 clusters)
    const int ty = t >> 4;         // point group (4 points)
    const int p0 = blockIdx.x * 64;
    const int lp = t >> 2;         // 0..63: row to stage
    const int lk = (t & 3) * 8;    // dim offset within k-tile

    float acc[4][4];
#pragma unroll
    for (int i = 0; i < 4; ++i)
#pragma unroll
        for (int j = 0; j < 4; ++j) acc[i][j] = 0.f;

    for (int kt = 0; kt < 12; ++kt) {
        const int k0 = kt * 32;
        float4 a0 = *(const float4*)(x + (size_t)(p0 + lp) * DIM + k0 + lk);
        float4 a1 = *(const float4*)(x + (size_t)(p0 + lp) * DIM + k0 + lk + 4);
        At[lk + 0][lp] = a0.x; At[lk + 1][lp] = a0.y;
        At[lk + 2][lp] = a0.z; At[lk + 3][lp] = a0.w;
        At[lk + 4][lp] = a1.x; At[lk + 5][lp] = a1.y;
        At[lk + 6][lp] = a1.z; At[lk + 7][lp] = a1.w;
        float4 b0 = *(const float4*)(centers + (size_t)lp * DIM + k0 + lk);
        float4 b1 = *(const float4*)(centers + (size_t)lp * DIM + k0 + lk + 4);
        Bt[lk + 0][lp] = b0.x; Bt[lk + 1][lp] = b0.y;
        Bt[lk + 2][lp] = b0.z; Bt[lk + 3][lp] = b0.w;
        Bt[lk + 4][lp] = b1.x; Bt[lk + 5][lp] = b1.y;
        Bt[lk + 6][lp] = b1.z; Bt[lk + 7][lp] = b1.w;
        __syncthreads();
#pragma unroll
        for (int kk = 0; kk < 32; ++kk) {
            float4 a4 = *(const float4*)&At[kk][ty * 4];
            float4 b4 = *(const float4*)&Bt[kk][tx * 4];
            float av[4] = {a4.x, a4.y, a4.z, a4.w};
            float bv[4] = {b4.x, b4.y, b4.z, b4.w};
#pragma unroll
            for (int i = 0; i < 4; ++i)
#pragma unroll
                for (int j = 0; j < 4; ++j) acc[i][j] += av[i] * bv[j];
        }
        __syncthreads();
    }

    float cn[4];
#pragma unroll
    for (int j = 0; j < 4; ++j) cn[j] = cnorm[tx * 4 + j];
#pragma unroll
    for (int i = 0; i < 4; ++i) {
        float bv = 3.4e38f; int bc = 0;
#pragma unroll
        for (int j = 0; j < 4; ++j) {
            float d = cn[j] - 2.0f * acc[i][j];
            if (d < bv) { bv = d; bc = tx * 4 + j; }  // strict <: lowest index wins ties
        }
        rv[ty * 4 + i][tx] = bv;
        rc[ty * 4 + i][tx] = bc;
    }
    __syncthreads();
    if (t < 64) {
        float bv = rv[t][0]; int bc = rc[t][0];
#pragma unroll
        for (int xx = 1; xx < 16; ++xx) {
            float v = rv[t][xx];
            if (v < bv) { bv = v; bc = rc[t][xx]; }  // ascending tx: lowest cluster wins ties
        }
        labels[p0 + t] = bc;
    }
}

// dim-parallel accumulation: thread t owns dim t; wave-uniform label -> no
// bank conflicts, no atomics in the hot loop. 96KB LDS sum table per block.
__global__ __launch_bounds__(384) void accum_kernel(const float* __restrict__ x,
                                                    const int* __restrict__ labels,
                                                    float* __restrict__ sums,
                                                    float* __restrict__ cnt) {
    __shared__ float lsum[KCL * DIM];   // 98304 B
    __shared__ int   llab[APTS];
    __shared__ int   lcnt[KCL];
    const int t = threadIdx.x;
    for (int i = t; i < KCL * DIM; i += 384) lsum[i] = 0.f;
    if (t < KCL) lcnt[t] = 0;
    const int p0 = blockIdx.x * APTS;
    if (t < APTS) llab[t] = labels[p0 + t];
    __syncthreads();
    if (t < APTS) atomicAdd(&lcnt[llab[t]], 1);

    const float* xp = x + (size_t)p0 * DIM + t;
#pragma unroll 1
    for (int i = 0; i < APTS; i += 4) {
        const int l0 = llab[i + 0], l1 = llab[i + 1];
        const int l2 = llab[i + 2], l3 = llab[i + 3];
        const float v0 = xp[(size_t)(i + 0) * DIM];
        const float v1 = xp[(size_t)(i + 1) * DIM];
        const float v2 = xp[(size_t)(i + 2) * DIM];
        const float v3 = xp[(size_t)(i + 3) * DIM];
        lsum[l0 * DIM + t] += v0;
        lsum[l1 * DIM + t] += v1;
        lsum[l2 * DIM + t] += v2;
        lsum[l3 * DIM + t] += v3;
    }
    __syncthreads();
    for (int i = t; i < KCL * DIM; i += 384) {
        float v = lsum[i];
        if (v != 0.f) atomicAdd(&sums[i], v);
    }
    if (t < KCL && lcnt[t] > 0) atomicAdd(&cnt[t], (float)lcnt[t]);
}

// centers[c] = cnt>0 ? sums/cnt : old ; cnorm ; re-zero sums/cnt for next iter
__global__ __launch_bounds__(384) void update_kernel(float* __restrict__ sums,
                                                     float* __restrict__ cnt,
                                                     float* __restrict__ centers,
                                                     float* __restrict__ cnorm) {
    __shared__ float red[384];
    const int c = blockIdx.x, t = threadIdx.x;
    float s = sums[(size_t)c * DIM + t];
    float n = cnt[c];
    float oldv = centers[(size_t)c * DIM + t];
    float nc = (n > 0.f) ? (s / n) : oldv;
    centers[(size_t)c * DIM + t] = nc;
    sums[(size_t)c * DIM + t] = 0.f;
    if (t == 0) cnt[c] = 0.f;
    red[t] = nc * nc;
    __syncthreads();
    if (t < 128) red[t] = red[t] + red[t + 128] + red[t + 256];
    __syncthreads();
    for (int st = 64; st > 0; st >>= 1) {
        if (t < st) red[t] += red[t + st];
        __syncthreads();
    }
    if (t == 0) cnorm[c] = red[0];
}

// CW[c][j] = b[j] + sum_d centers[c][d] * W[j][d]
__global__ __launch_bounds__(384) void cw_kernel(const float* __restrict__ centers,
                                                 const float* __restrict__ W,
                                                 const float* __restrict__ b,
                                                 float* __restrict__ CW) {
    __shared__ float cs[DIM];
    const int c = blockIdx.x, j = threadIdx.x;
    cs[j] = centers[(size_t)c * DIM + j];
    __syncthreads();
    float acc = b[j];
    const float* wr = W + (size_t)j * DIM;
    for (int d4 = 0; d4 < 96; ++d4) {
        float4 v = *(const float4*)(wr + d4 * 4);
        acc += cs[d4 * 4 + 0] * v.x + cs[d4 * 4 + 1] * v.y
             + cs[d4 * 4 + 2] * v.z + cs[d4 * 4 + 3] * v.w;
    }
    CW[(size_t)c * DIM + j] = acc;
}

// fused final assignment + output write: out[p][:] = CW[argmin_c d(p,c)][:]
__global__ __launch_bounds__(256) void final_kernel(const float* __restrict__ x,
                                                    const float* __restrict__ centers,
                                                    const float* __restrict__ cnorm,
                                                    const float* __restrict__ CW,
                                                    float* __restrict__ out) {
    __shared__ float At[32][68];
    __shared__ float Bt[32][68];
    __shared__ float rv[64][16];
    __shared__ int   rc[64][16];
    __shared__ int   lab[64];
    const int t  = threadIdx.x;
    const int tx = t & 15;
    const int ty = t >> 4;
    const int p0 = blockIdx.x * 64;
    const int lp = t >> 2;
    const int lk = (t & 3) * 8;

    float acc[4][4];
#pragma unroll
    for (int i = 0; i < 4; ++i)
#pragma unroll
        for (int j = 0; j < 4; ++j) acc[i][j] = 0.f;

    for (int kt = 0; kt < 12; ++kt) {
        const int k0 = kt * 32;
        float4 a0 = *(const float4*)(x + (size_t)(p0 + lp) * DIM + k0 + lk);
        float4 a1 = *(const float4*)(x + (size_t)(p0 + lp) * DIM + k0 + lk + 4);
        At[lk + 0][lp] = a0.x; At[lk + 1][lp] = a0.y;
        At[lk + 2][lp] = a0.z; At[lk + 3][lp] = a0.w;
        At[lk + 4][lp] = a1.x; At[lk + 5][lp] = a1.y;
        At[lk + 6][lp] = a1.z; At[lk + 7][lp] = a1.w;
        float4 b0 = *(const float4*)(centers + (size_t)lp * DIM + k0 + lk);
        float4 b1 = *(const float4*)(centers + (size_t)lp * DIM + k0 + lk + 4);
        Bt[lk + 0][lp] = b0.x; Bt[lk + 1][lp] = b0.y;
        Bt[lk + 2][lp] = b0.z; Bt[lk + 3][lp] = b0.w;
        Bt[lk + 4][lp] = b1.x; Bt[lk + 5][lp] = b1.y;
        Bt[lk + 6][lp] = b1.z; Bt[lk + 7][lp] = b1.w;
        __syncthreads();
#pragma unroll
        for (int kk = 0; kk < 32; ++kk) {
            float4 a4 = *(const float4*)&At[kk][ty * 4];
            float4 b4 = *(const float4*)&Bt[kk][tx * 4];
            float av[4] = {a4.x, a4.y, a4.z, a4.w};
            float bv[4] = {b4.x, b4.y, b4.z, b4.w};
#pragma unroll
            for (int i = 0; i < 4; ++i)
#pragma unroll
                for (int j = 0; j < 4; ++j) acc[i][j] += av[i] * bv[j];
        }
        __syncthreads();
    }

    float cn[4];
#pragma unroll
    for (int j = 0; j < 4; ++j) cn[j] = cnorm[tx * 4 + j];
#pragma unroll
    for (int i = 0; i < 4; ++i) {
        float bv = 3.4e38f; int bc = 0;
#pragma unroll
        for (int j = 0; j < 4; ++j) {
            float d = cn[j] - 2.0f * acc[i][j];
            if (d < bv) { bv = d; bc = tx * 4 + j; }
        }
        rv[ty * 4 + i][tx] = bv;
        rc[ty * 4 + i][tx] = bc;
    }
    __syncthreads();
    if (t < 64) {
        float bv = rv[t][0]; int bc = rc[t][0];
#pragma unroll
        for (int xx = 1; xx < 16; ++xx) {
            float v = rv[t][xx];
            if (v < bv) { bv = v; bc = rc[t][xx]; }
        }
        lab[t] = bc;
    }
    __syncthreads();
    // write 64 points x 384 floats = 6144 float4 chunks; 24 per thread
#pragma unroll
    for (int r = 0; r < 24; ++r) {
        const int q = r * 256 + t;
        const int pp = q / 96;
        const int jg = q - pp * 96;
        float4 v = *(const float4*)(CW + (size_t)lab[pp] * DIM + jg * 4);
        *(float4*)(out + (size_t)(p0 + pp) * DIM + jg * 4) = v;
    }
}

extern "C" void kernel_launch(void* const* d_in, const int* in_sizes, int n_in,
                              void* d_out, int out_size, void* d_ws, size_t ws_size,
                              hipStream_t stream) {
    const float* x = (const float*)d_in[0];  // fp32 (16,4096,384)
    const float* W = (const float*)d_in[1];  // fp32 (384,384)
    const float* b = (const float*)d_in[2];  // fp32 (384,)
    float* out = (float*)d_out;              // fp32 (16,4096,384)

    float* centers = (float*)d_ws;                 // 64*384
    float* sums    = centers + KCL * DIM;          // 64*384
    float* cnorm   = sums + KCL * DIM;             // 64
    float* cnt     = cnorm + KCL;                  // 64
    float* CW      = cnt + KCL;                    // 64*384
    int* labels = (int*)d_out;                     // head of d_out (dead before final)

    init_kernel<<<KCL, 384, 0, stream>>>(x, centers, sums, cnorm, cnt);
    for (int it = 0; it < ITERS; ++it) {
        assign_kernel<<<P_TOT / 64, 256, 0, stream>>>(x, centers, cnorm, labels);
        accum_kernel<<<P_TOT / APTS, 384, 0, stream>>>(x, labels, sums, cnt);
        update_kernel<<<KCL, 384, 0, stream>>>(sums, cnt, centers, cnorm);
    }
    cw_kernel<<<KCL, 384, 0, stream>>>(centers, W, b, CW);
    final_kernel<<<P_TOT / 64, 256, 0, stream>>>(x, centers, cnorm, CW, out);
}